// Round 4
// baseline (361.975 us; speedup 1.0000x reference)
//
#include <hip/hip_runtime.h>
#include <math.h>
#include <stdint.h>

// Problem constants (fixed by setup_inputs)
constexpr int nB = 16, nA = 3, nH = 128, nW = 128, nC = 80;
constexpr int HW = nH * nW;                 // 16384
constexpr int NPOS = nB * nA * HW;          // 786432
constexpr int TPB = 128;                    // threads/block == positions/block
constexpr int SEG = 20;                     // float4 segments per 80-float cls row
constexpr int PAD = 21;                     // padded LDS row stride

__device__ __forceinline__ float sigmoidf_fast(float x) {
    return 1.0f / (1.0f + __expf(-x));
}

__global__ __launch_bounds__(TPB) void yolo_decode_kernel(
    const float* __restrict__ t_xywha,   // [NPOS,5]
    const float* __restrict__ conf,      // [NPOS]
    const float* __restrict__ cls,       // [NPOS,80]
    const float* __restrict__ anchors,   // [nA,2]
    float* __restrict__ out)             // [NPOS*5 | NPOS | NPOS]
{
    __shared__ uint64_t keys[TPB * PAD]; // packed (monotonic-max | inv-idx) per (pos,seg)
    __shared__ float txy[TPB * 5];       // staging for t_xywha / p_xywha rows

    const int t    = threadIdx.x;
    const int base = blockIdx.x * TPB;

    // ---- phase A: fully contiguous cls loads; one packed u64 per float4 ----
    const float4* __restrict__ c4 = (const float4*)(cls + (long long)base * nC);
    int p = t / 20, s = t % 20;
    #pragma unroll
    for (int i = 0; i < SEG; ++i) {
        const float4 v = c4[t + TPB * i];
        float m = v.x; int sub = 0;                 // first-wins within the 4
        if (v.y > m) { m = v.y; sub = 1; }
        if (v.z > m) { m = v.z; sub = 2; }
        if (v.w > m) { m = v.w; sub = 3; }
        const uint32_t b  = __float_as_uint(m);
        // order-preserving float->uint: pos -> b|0x80000000-ish, neg -> ~b
        const uint32_t mk = b ^ ((uint32_t)((int32_t)b >> 31) | 0x80000000u);
        const uint32_t lo = 0xFFFFu - (uint32_t)(4 * s + sub); // smaller idx wins ties
        keys[p * PAD + s] = ((uint64_t)mk << 32) | lo;
        p += 6; s += 8; if (s >= 20) { s -= 20; p += 1; }      // f += 128
    }

    // stage t_xywha rows (contiguous), issue conf load early
    const float* __restrict__ txyg = t_xywha + (long long)base * 5;
    #pragma unroll
    for (int i = 0; i < 5; ++i) txy[t + TPB * i] = txyg[t + TPB * i];

    const int q = base + t;
    const float cfl = conf[q];

    __syncthreads();

    // ---- phase B: branch-free u64-max over 20 packed partials ----
    uint64_t best = 0;                               // no NaNs in input; 0 is identity
    #pragma unroll
    for (int s2 = 0; s2 < SEG; ++s2) {
        const uint64_t k = keys[t * PAD + s2];
        best = (k > best) ? k : best;
    }
    const uint32_t mk2  = (uint32_t)(best >> 32);
    const uint32_t msk  = (uint32_t)((int32_t)(~mk2) >> 31) | 0x80000000u;
    const float    m    = __uint_as_float(mk2 ^ msk);
    const int      idx  = (int)(0xFFFFu - (uint32_t)(best & 0xFFFFFFFFu));

    const int w = q & 127;
    const int h = (q >> 7) & 127;
    const int a = (q >> 14) % 3;

    const float tx = txy[5 * t + 0], ty = txy[5 * t + 1];
    const float tw = txy[5 * t + 2], th = txy[5 * t + 3];
    const float ta = txy[5 * t + 4];
    const float aw = anchors[2 * a + 0];
    const float ah = anchors[2 * a + 1];

    const float px   = (sigmoidf_fast(tx) + (float)w) * 8.0f;   // STRIDE = 8
    const float py   = (sigmoidf_fast(ty) + (float)h) * 8.0f;
    const float pw   = __expf(tw) * aw;
    const float ph   = __expf(th) * ah;
    const float pdeg = sigmoidf_fast(ta) * 360.0f - 180.0f;     // sig*2pi-pi -> deg
    const float cf   = sigmoidf_fast(cfl) * sigmoidf_fast(m);

    // coalesced, nontemporal idx/conf stores (never re-read)
    __builtin_nontemporal_store((float)idx, out + (long long)NPOS * 5 + q);
    __builtin_nontemporal_store(cf,         out + (long long)NPOS * 6 + q);

    // stage p_xywha into own LDS row, then contiguous nontemporal stores
    txy[5 * t + 0] = px; txy[5 * t + 1] = py; txy[5 * t + 2] = pw;
    txy[5 * t + 3] = ph; txy[5 * t + 4] = pdeg;
    __syncthreads();

    float* __restrict__ og = out + (long long)base * 5;
    #pragma unroll
    for (int i = 0; i < 5; ++i)
        __builtin_nontemporal_store(txy[t + TPB * i], og + t + TPB * i);
}

extern "C" void kernel_launch(void* const* d_in, const int* in_sizes, int n_in,
                              void* d_out, int out_size, void* d_ws, size_t ws_size,
                              hipStream_t stream) {
    const float* t_xywha = (const float*)d_in[0];
    const float* conf    = (const float*)d_in[1];
    const float* cls     = (const float*)d_in[2];
    const float* anchors = (const float*)d_in[3];
    float* out = (float*)d_out;

    dim3 grid(NPOS / TPB);   // 6144 blocks
    dim3 block(TPB);
    yolo_decode_kernel<<<grid, block, 0, stream>>>(t_xywha, conf, cls, anchors, out);
}